// Round 16
// baseline (786.801 us; speedup 1.0000x reference)
//
#include <hip/hip_runtime.h>

#define IN_F  32
#define HID_F 64
#define OUT_F 32

#define BKT_SHIFT 8            // 256 nodes per bucket
#define BKT_NODES 256
#define NBLK      512          // partition blocks — count/append edge->block map MUST match
#define DBINS     64           // degree bins for node sort

// bf16 helpers (round-to-nearest-even; inputs are finite)
__device__ inline unsigned short f2bf(float f) {
    unsigned u = __float_as_uint(f);
    return (unsigned short)((u + 0x7FFF + ((u >> 16) & 1)) >> 16);
}
// packed-pair unpack: word = (bf16 hi << 16) | bf16 lo ; lo = even feature
__device__ inline float bflo(unsigned w) { return __uint_as_float(w << 16); }
__device__ inline float bfhi(unsigned w) { return __uint_as_float(w & 0xFFFF0000u); }

// ================= phase 1: per-(bucket,block) exact counts =================
__global__ __launch_bounds__(256) void count_kernel(const int* __restrict__ dst,
                                                    int* __restrict__ cnt, int E, int nb)
{
    __shared__ int hist[1024];          // nb <= 1024
    int tid = threadIdx.x;
    for (int i = tid; i < nb; i += 256) hist[i] = 0;
    __syncthreads();
    for (int e = blockIdx.x * 256 + tid; e < E; e += NBLK * 256)
        atomicAdd(&hist[dst[e] >> BKT_SHIFT], 1);
    __syncthreads();
    for (int i = tid; i < nb; i += 256) cnt[i * NBLK + blockIdx.x] = hist[i];
}

// ================= phase 2a: per-bucket totals =================
__global__ __launch_bounds__(NBLK) void bsum_kernel(const int* __restrict__ cnt,
                                                    int* __restrict__ bsum)
{
    __shared__ int s[NBLK];
    int tid = threadIdx.x, b = blockIdx.x;
    s[tid] = cnt[b * NBLK + tid];
    __syncthreads();
    for (int off = NBLK / 2; off > 0; off >>= 1) {
        if (tid < off) s[tid] += s[tid + off];
        __syncthreads();
    }
    if (tid == 0) bsum[b] = s[0];
}

// ================= phase 2b: one-block exclusive scan of bucket totals =================
__global__ __launch_bounds__(512) void bscan_kernel(int* __restrict__ bsum, int nb,
                                                    int* __restrict__ cellstart, int nc,
                                                    int* __restrict__ rowstart, int n, int E)
{
    __shared__ int s[512];
    int tid = threadIdx.x;
    int my = (tid < nb) ? bsum[tid] : 0;
    s[tid] = my;
    __syncthreads();
    for (int off = 1; off < 512; off <<= 1) {
        int t = (tid >= off) ? s[tid - off] : 0;
        __syncthreads();
        s[tid] += t;
        __syncthreads();
    }
    if (tid < nb) bsum[tid] = s[tid] - my;      // exclusive bucket start
    if (tid == 0) { cellstart[nc] = E; rowstart[n] = E; }
}

// ================= phase 2c: per-bucket scan of its NBLK cells =================
__global__ __launch_bounds__(NBLK) void cscan_kernel(const int* __restrict__ cnt,
                                                     const int* __restrict__ bsum,
                                                     int* __restrict__ cellstart)
{
    __shared__ int s[NBLK];
    int tid = threadIdx.x, b = blockIdx.x;
    int my = cnt[b * NBLK + tid];
    s[tid] = my;
    __syncthreads();
    for (int off = 1; off < NBLK; off <<= 1) {
        int t = (tid >= off) ? s[tid - off] : 0;
        __syncthreads();
        s[tid] += t;
        __syncthreads();
    }
    cellstart[b * NBLK + tid] = bsum[b] + s[tid] - my;   // exclusive
}

// ================= phase 3: append via block-private LDS cursors =================
__global__ __launch_bounds__(256) void append_kernel(
    const int* __restrict__ src, const int* __restrict__ dst,
    const int* __restrict__ cellstart, unsigned* __restrict__ pairs, int E, int nb)
{
    __shared__ int cur[1024];
    int tid = threadIdx.x;
    for (int i = tid; i < nb; i += 256) cur[i] = cellstart[i * NBLK + blockIdx.x];
    __syncthreads();
    for (int e = blockIdx.x * 256 + tid; e < E; e += NBLK * 256) {
        int d = dst[e];
        int pos = atomicAdd(&cur[d >> BKT_SHIFT], 1);     // LDS atomic
        pairs[pos] = ((unsigned)src[e] << BKT_SHIFT) | (unsigned)(d & (BKT_NODES - 1));
    }
}

// ================= phase 4: place + rowstart + dinv + xs build + degree histogram =====
__global__ __launch_bounds__(256) void place_kernel(
    const int* __restrict__ cellstart, const unsigned* __restrict__ pairs,
    const float* __restrict__ x,
    int* __restrict__ srcs, int* __restrict__ rowstart, float* __restrict__ dinv,
    unsigned* __restrict__ xs2, int* __restrict__ deghist, int n)
{
    __shared__ int hist[BKT_NODES];
    __shared__ int ofs[BKT_NODES];
    __shared__ float sdinv[BKT_NODES];
    int b = blockIdx.x, tid = threadIdx.x;
    int beg = cellstart[b * NBLK], end = cellstart[(b + 1) * NBLK];
    hist[tid] = 0;
    __syncthreads();
    for (int e = beg + tid; e < end; e += 256)
        atomicAdd(&hist[pairs[e] & (BKT_NODES - 1)], 1);
    __syncthreads();
    int my = hist[tid];
    ofs[tid] = my;
    __syncthreads();
    for (int off = 1; off < 256; off <<= 1) {
        int t = (tid >= off) ? ofs[tid - off] : 0;
        __syncthreads();
        ofs[tid] += t;
        __syncthreads();
    }
    int excl = ofs[tid] - my;
    int node = b * BKT_NODES + tid;
    float dv = rsqrtf((float)(my + 1));   // +1 self-loop
    sdinv[tid] = dv;
    if (node < n) {
        rowstart[node] = beg + excl;
        dinv[node] = dv;
        atomicAdd(&deghist[min(my, DBINS - 1)], 1);   // degree-sort histogram
    }
    __syncthreads();
    ofs[tid] = excl;                    // reuse as LDS cursor
    __syncthreads();
    for (int e = beg + tid; e < end; e += 256) {
        unsigned p = pairs[e];
        int dl = p & (BKT_NODES - 1);
        int pos = beg + atomicAdd(&ofs[dl], 1);
        srcs[pos] = (int)(p >> BKT_SHIFT);
    }
    // fused xs build: xs2[node][q] = packed bf16 pair of dinv[node]*x[node][2q..2q+1]
    const float4* x4 = (const float4*)x;
    uint2* xo = (uint2*)xs2;
    for (int idx = tid; idx < BKT_NODES * 8; idx += 256) {
        int nloc = idx >> 3, g = idx & 7;
        int nd = b * BKT_NODES + nloc;
        if (nd < n) {
            float d = sdinv[nloc];
            float4 v = x4[((size_t)nd << 3) + g];
            unsigned lo = (unsigned)f2bf(v.x * d) | ((unsigned)f2bf(v.y * d) << 16);
            unsigned hi = (unsigned)f2bf(v.z * d) | ((unsigned)f2bf(v.w * d) << 16);
            xo[((size_t)nd << 3) + g] = make_uint2(lo, hi);
        }
    }
}

// ================= degree-bin scan (1 block, 64 threads) =================
__global__ __launch_bounds__(DBINS) void binscan_kernel(const int* __restrict__ deghist,
                                                        int* __restrict__ bincur)
{
    __shared__ int s[DBINS];
    int tid = threadIdx.x;
    int my = deghist[tid];
    s[tid] = my;
    __syncthreads();
    for (int off = 1; off < DBINS; off <<= 1) {
        int t = (tid >= off) ? s[tid - off] : 0;
        __syncthreads();
        s[tid] += t;
        __syncthreads();
    }
    bincur[tid] = s[tid] - my;   // exclusive
}

// ================= perm fill: counting-sort nodes by degree =================
__global__ void permfill_kernel(const int* __restrict__ rowstart, int* __restrict__ bincur,
                                int* __restrict__ perm, int n)
{
    int node = blockIdx.x * blockDim.x + threadIdx.x;
    if (node < n) {
        int deg = rowstart[node + 1] - rowstart[node];
        int pos = atomicAdd(&bincur[min(deg, DBINS - 1)], 1);
        perm[pos] = node;
    }
}

// ================= fused1: degree-uniform quarter-wave gather -> MLP =================
// 16 nodes/block via perm (degree-sorted -> near-zero wave divergence).
__global__ __launch_bounds__(256) void fused1_kernel(
    const int* __restrict__ perm,
    const int* __restrict__ rowstart, const int* __restrict__ srcs,
    const unsigned* __restrict__ xs2, const float* __restrict__ dinv,
    const float* __restrict__ b1, const float* __restrict__ W1,
    const float* __restrict__ W2, unsigned* __restrict__ hs2p, int n)
{
    __shared__ float W1s[IN_F * HID_F];    // 8 KB  [k*64+j]
    __shared__ float W2s[HID_F * OUT_F];   // 8 KB  [k*32+j]
    __shared__ float grow[16][IN_F + 1];   // padded
    __shared__ float hrow[16][HID_F + 1];  // padded
    int tid = threadIdx.x;
    for (int t = tid; t < IN_F * HID_F; t += 256) W1s[t] = W1[t];
    for (int t = tid; t < HID_F * OUT_F; t += 256) W2s[t] = W2[t];

    int nl = tid >> 4;
    unsigned q = tid & 15;
    int g = blockIdx.x * 16 + nl;
    bool active = g < n;
    int node = active ? perm[g] : 0;

    int beg = rowstart[node], end = active ? rowstart[node + 1] : beg;
    unsigned ws = active ? xs2[((unsigned)node << 4) + q] : 0u;   // self-loop
    float a0l = bflo(ws), a0h = bfhi(ws);
    float a1l = 0.f, a1h = 0.f, a2l = 0.f, a2h = 0.f, a3l = 0.f, a3h = 0.f;
    float a4l = 0.f, a4h = 0.f, a5l = 0.f, a5h = 0.f, a6l = 0.f, a6h = 0.f;
    float a7l = 0.f, a7h = 0.f;
    int e = beg;
    for (; e + 8 <= end; e += 8) {
        unsigned o0 = ((unsigned)srcs[e]     << 4) + q, o1 = ((unsigned)srcs[e + 1] << 4) + q;
        unsigned o2 = ((unsigned)srcs[e + 2] << 4) + q, o3 = ((unsigned)srcs[e + 3] << 4) + q;
        unsigned o4 = ((unsigned)srcs[e + 4] << 4) + q, o5 = ((unsigned)srcs[e + 5] << 4) + q;
        unsigned o6 = ((unsigned)srcs[e + 6] << 4) + q, o7 = ((unsigned)srcs[e + 7] << 4) + q;
        unsigned w0 = xs2[o0], w1 = xs2[o1], w2 = xs2[o2], w3 = xs2[o3];
        unsigned w4 = xs2[o4], w5 = xs2[o5], w6 = xs2[o6], w7 = xs2[o7];
        a0l += bflo(w0); a0h += bfhi(w0); a1l += bflo(w1); a1h += bfhi(w1);
        a2l += bflo(w2); a2h += bfhi(w2); a3l += bflo(w3); a3h += bfhi(w3);
        a4l += bflo(w4); a4h += bfhi(w4); a5l += bflo(w5); a5h += bfhi(w5);
        a6l += bflo(w6); a6h += bfhi(w6); a7l += bflo(w7); a7h += bfhi(w7);
    }
    for (; e + 4 <= end; e += 4) {
        unsigned o0 = ((unsigned)srcs[e]     << 4) + q, o1 = ((unsigned)srcs[e + 1] << 4) + q;
        unsigned o2 = ((unsigned)srcs[e + 2] << 4) + q, o3 = ((unsigned)srcs[e + 3] << 4) + q;
        unsigned w0 = xs2[o0], w1 = xs2[o1], w2 = xs2[o2], w3 = xs2[o3];
        a0l += bflo(w0); a0h += bfhi(w0); a1l += bflo(w1); a1h += bfhi(w1);
        a2l += bflo(w2); a2h += bfhi(w2); a3l += bflo(w3); a3h += bfhi(w3);
    }
    for (; e < end; ++e) {
        unsigned w0 = xs2[((unsigned)srcs[e] << 4) + q];
        a0l += bflo(w0); a0h += bfhi(w0);
    }
    float dv = dinv[node];
    grow[nl][2 * q]     = dv * (((a0l + a1l) + (a2l + a3l)) + ((a4l + a5l) + (a6l + a7l)));
    grow[nl][2 * q + 1] = dv * (((a0h + a1h) + (a2h + a3h)) + ((a4h + a5h) + (a6h + a7h)));
    __syncthreads();

    // ---- MLP: 16 threads/node. hidden features q, q+16, q+32, q+48 ----
    float h0 = b1[q], h1 = b1[q + 16], h2 = b1[q + 32], h3 = b1[q + 48];
    #pragma unroll
    for (int k = 0; k < IN_F; ++k) {
        float gk = grow[nl][k];
        h0 += gk * W1s[k * HID_F + q];
        h1 += gk * W1s[k * HID_F + q + 16];
        h2 += gk * W1s[k * HID_F + q + 32];
        h3 += gk * W1s[k * HID_F + q + 48];
    }
    hrow[nl][q]      = fmaxf(h0, 0.f);
    hrow[nl][q + 16] = fmaxf(h1, 0.f);
    hrow[nl][q + 32] = fmaxf(h2, 0.f);
    hrow[nl][q + 48] = fmaxf(h3, 0.f);
    __syncthreads();

    // ---- W2 matvec: output features 2q, 2q+1; write packed pair ----
    float p0 = 0.f, p1 = 0.f;
    #pragma unroll
    for (int k = 0; k < HID_F; ++k) {
        float hk = hrow[nl][k];
        p0 += hk * W2s[k * OUT_F + 2 * q];
        p1 += hk * W2s[k * OUT_F + 2 * q + 1];
    }
    if (active) {
        unsigned pack = (unsigned)f2bf(dv * p0) | ((unsigned)f2bf(dv * p1) << 16);
        hs2p[((unsigned)node << 4) + q] = pack;
    }
}

// ================= agg2: degree-uniform quarter-wave gather of hs2p, finalize =====
__global__ __launch_bounds__(256) void agg2_kernel(
    const int* __restrict__ perm,
    const int* __restrict__ rowstart, const int* __restrict__ srcs,
    const unsigned* __restrict__ hs2p, const float* __restrict__ dinv,
    const float* __restrict__ b2, float* __restrict__ out, int n)
{
    int t = blockIdx.x * blockDim.x + threadIdx.x;
    int g = t >> 4;
    if (g >= n) return;
    int node = perm[g];
    unsigned q = t & 15;
    int beg = rowstart[node], end = rowstart[node + 1];
    unsigned ws = hs2p[((unsigned)node << 4) + q];   // self-loop
    float a0l = bflo(ws), a0h = bfhi(ws);
    float a1l = 0.f, a1h = 0.f, a2l = 0.f, a2h = 0.f, a3l = 0.f, a3h = 0.f;
    float a4l = 0.f, a4h = 0.f, a5l = 0.f, a5h = 0.f, a6l = 0.f, a6h = 0.f;
    float a7l = 0.f, a7h = 0.f;
    int e = beg;
    for (; e + 8 <= end; e += 8) {
        unsigned o0 = ((unsigned)srcs[e]     << 4) + q, o1 = ((unsigned)srcs[e + 1] << 4) + q;
        unsigned o2 = ((unsigned)srcs[e + 2] << 4) + q, o3 = ((unsigned)srcs[e + 3] << 4) + q;
        unsigned o4 = ((unsigned)srcs[e + 4] << 4) + q, o5 = ((unsigned)srcs[e + 5] << 4) + q;
        unsigned o6 = ((unsigned)srcs[e + 6] << 4) + q, o7 = ((unsigned)srcs[e + 7] << 4) + q;
        unsigned w0 = hs2p[o0], w1 = hs2p[o1], w2 = hs2p[o2], w3 = hs2p[o3];
        unsigned w4 = hs2p[o4], w5 = hs2p[o5], w6 = hs2p[o6], w7 = hs2p[o7];
        a0l += bflo(w0); a0h += bfhi(w0); a1l += bflo(w1); a1h += bfhi(w1);
        a2l += bflo(w2); a2h += bfhi(w2); a3l += bflo(w3); a3h += bfhi(w3);
        a4l += bflo(w4); a4h += bfhi(w4); a5l += bflo(w5); a5h += bfhi(w5);
        a6l += bflo(w6); a6h += bfhi(w6); a7l += bflo(w7); a7h += bfhi(w7);
    }
    for (; e + 4 <= end; e += 4) {
        unsigned o0 = ((unsigned)srcs[e]     << 4) + q, o1 = ((unsigned)srcs[e + 1] << 4) + q;
        unsigned o2 = ((unsigned)srcs[e + 2] << 4) + q, o3 = ((unsigned)srcs[e + 3] << 4) + q;
        unsigned w0 = hs2p[o0], w1 = hs2p[o1], w2 = hs2p[o2], w3 = hs2p[o3];
        a0l += bflo(w0); a0h += bfhi(w0); a1l += bflo(w1); a1h += bfhi(w1);
        a2l += bflo(w2); a2h += bfhi(w2); a3l += bflo(w3); a3h += bfhi(w3);
    }
    for (; e < end; ++e) {
        unsigned w0 = hs2p[((unsigned)srcs[e] << 4) + q];
        a0l += bflo(w0); a0h += bfhi(w0);
    }
    float dvv = dinv[node];
    float2 r;
    r.x = dvv * (((a0l + a1l) + (a2l + a3l)) + ((a4l + a5l) + (a6l + a7l))) + b2[2 * q];
    r.y = dvv * (((a0h + a1h) + (a2h + a3h)) + ((a4h + a5h) + (a6h + a7h))) + b2[2 * q + 1];
    ((float2*)out)[((size_t)node << 4) + q] = r;
}

extern "C" void kernel_launch(void* const* d_in, const int* in_sizes, int n_in,
                              void* d_out, int out_size, void* d_ws, size_t ws_size,
                              hipStream_t stream) {
    const float* x  = (const float*)d_in[0];
    const int*   ei = (const int*)  d_in[1];
    const float* W1 = (const float*)d_in[2];
    const float* b1 = (const float*)d_in[3];
    const float* W2 = (const float*)d_in[4];
    const float* b2 = (const float*)d_in[5];
    float* out = (float*)d_out;

    const int n = in_sizes[0] / IN_F;     // 100000
    const int E = in_sizes[1] / 2;        // 1600000
    const int* src = ei;
    const int* dst = ei + E;

    const int nb = (n + BKT_NODES - 1) >> BKT_SHIFT;   // 391 buckets (<=512)
    const int nc = nb * NBLK;                          // 200192 cells

    // ---- workspace layout: ~28 MB ----
    int* ip = (int*)d_ws;
    int* cnt       = ip;                 ip += nc;         // 0.8 MB
    int* cellstart = ip;                 ip += nc + 1;     // 0.8 MB
    int* bsum      = ip;                 ip += nb + 1;
    int* rowstart  = ip;                 ip += n + 1;
    int* deghist   = ip;                 ip += DBINS;      // zeroed
    int* bincur    = ip;                 ip += DBINS;
    int* perm      = ip;                 ip += n;
    unsigned* pairs = (unsigned*)ip;     ip += E;          // 6.4 MB
    int* srcs_srt  = ip;                 ip += E;          // 6.4 MB
    float* dinv = (float*)ip;            ip += n;
    unsigned* xs2  = (unsigned*)ip;      ip += (size_t)n * IN_F / 2;   // 6.4 MB
    unsigned* hs2p = (unsigned*)ip;                                    // 6.4 MB

    hipMemsetAsync(deghist, 0, DBINS * sizeof(int), stream);

    count_kernel<<<NBLK, 256, 0, stream>>>(dst, cnt, E, nb);
    bsum_kernel <<<nb, NBLK, 0, stream>>>(cnt, bsum);
    bscan_kernel<<<1, 512, 0, stream>>>(bsum, nb, cellstart, nc, rowstart, n, E);
    cscan_kernel<<<nb, NBLK, 0, stream>>>(cnt, bsum, cellstart);
    append_kernel<<<NBLK, 256, 0, stream>>>(src, dst, cellstart, pairs, E, nb);
    place_kernel<<<nb, 256, 0, stream>>>(cellstart, pairs, x, srcs_srt, rowstart, dinv, xs2, deghist, n);
    binscan_kernel<<<1, DBINS, 0, stream>>>(deghist, bincur);
    permfill_kernel<<<(n + 255) / 256, 256, 0, stream>>>(rowstart, bincur, perm, n);

    fused1_kernel<<<(n + 15) / 16, 256, 0, stream>>>(perm, rowstart, srcs_srt, xs2, dinv, b1, W1, W2, hs2p, n);
    agg2_kernel<<<((size_t)n * 16 + 255) / 256, 256, 0, stream>>>(perm, rowstart, srcs_srt, hs2p, dinv, b2, out, n);
}